// Round 5
// baseline (446.492 us; speedup 1.0000x reference)
//
#include <hip/hip_runtime.h>
#include <hip/hip_bf16.h>
#include <math.h>

#define T_DIM 1024
#define B_DIM 8
#define D_DIM 1024
#define H_DIM 16
#define DH 64
#define M_ROWS 8192          // T*B
#define N_COLS 5120          // 5*D
#define K_DIM 1024
#define CT 32                // scan chunk (timesteps per LDS stage)
#define NCHUNK (T_DIM / CT)
#define REC 768              // bytes per (bh,t): [k fp32 x64][q fp32 x64][v fp32 x64]

typedef __attribute__((ext_vector_type(8))) short short8;
typedef __attribute__((ext_vector_type(4))) float floatx4;

static __device__ __forceinline__ unsigned short f2bf(float f){
    unsigned int u = __float_as_uint(f);
    u += 0x7fff + ((u >> 16) & 1);          // RNE
    return (unsigned short)(u >> 16);
}
static __device__ __forceinline__ float sigf(float x){
    return 1.f / (1.f + __expf(-x));
}

// DPP butterfly adds on VALU pipe: xor1=quad_perm[1,0,3,2]=0xB1,
// xor2=quad_perm[2,3,0,1]=0x4E, xor4=row_half_mirror=0x141, xor8=row_mirror=0x140
#define DPPADD(x, ctrl) ((x) + __int_as_float(__builtin_amdgcn_update_dpp(0, __float_as_int(x), (ctrl), 0xF, 0xF, true)))
static __device__ __forceinline__ float red16(float x){
    x = DPPADD(x, 0xB1); x = DPPADD(x, 0x4E); x = DPPADD(x, 0x141); x = DPPADD(x, 0x140); return x;
}
static __device__ __forceinline__ void red16x3(float& x, float& y, float& z){
    x = DPPADD(x, 0xB1);  y = DPPADD(y, 0xB1);  z = DPPADD(z, 0xB1);
    x = DPPADD(x, 0x4E);  y = DPPADD(y, 0x4E);  z = DPPADD(z, 0x4E);
    x = DPPADD(x, 0x141); y = DPPADD(y, 0x141); z = DPPADD(z, 0x141);
    x = DPPADD(x, 0x140); y = DPPADD(y, 0x140); z = DPPADD(z, 0x140);
}

// ---------------- fp32 -> bf16 conversion ----------------
__global__ void cvt_bf16(const float* __restrict__ src, unsigned short* __restrict__ dst, int n4){
    int i = blockIdx.x*blockDim.x + threadIdx.x;
    int stride = gridDim.x*blockDim.x;
    for (; i < n4; i += stride){
        float4 f = ((const float4*)src)[i];
        ushort4 o;
        o.x = f2bf(f.x); o.y = f2bf(f.y); o.z = f2bf(f.z); o.w = f2bf(f.w);
        ((ushort4*)dst)[i] = o;
    }
}

__global__ void cvt_w(const float* __restrict__ w0, const float* __restrict__ w1,
                      const float* __restrict__ w2, const float* __restrict__ w3,
                      const float* __restrict__ w4, unsigned short* __restrict__ dst){
    int i = blockIdx.x*blockDim.x + threadIdx.x;   // one float4 each; 5*262144 total
    int seg = i >> 18;
    int off = i & 262143;
    const float* src = (seg==0)?w0:(seg==1)?w1:(seg==2)?w2:(seg==3)?w3:w4;
    float4 f = ((const float4*)src)[off];
    ushort4 o;
    o.x = f2bf(f.x); o.y = f2bf(f.y); o.z = f2bf(f.z); o.w = f2bf(f.w);
    ((ushort4*)dst)[i] = o;
}

// ---------------- NT GEMM + fully fused epilogue ----------------
// n-tile 0..7: q -> l2-normalize rows -> KQV[rec][256..512)
// n-tile 8..15: k -> l2-normalize rows -> KQV[rec][0..256)
// n-tile 16..23: v -> KQV[rec][512..768)
// n-tile 24..31: alpha -> G[rec].x ; 32..39: beta -> G[rec].y
#define GLD16(g, l) __builtin_amdgcn_global_load_lds(                         \
    (const __attribute__((address_space(1))) void*)(g),                       \
    (__attribute__((address_space(3))) void*)(l), 16, 0, 0)

__global__ __launch_bounds__(256) void gemm_bt(const unsigned short* __restrict__ A,
                                               const unsigned short* __restrict__ B,
                                               unsigned char* __restrict__ KQV,
                                               float* __restrict__ G,
                                               const float* __restrict__ b_alpha,
                                               const float* __restrict__ b_beta){
    __shared__ unsigned short As[128*32];
    __shared__ unsigned short Bs[128*32];
    const int tid = threadIdx.x;
    const int rowBase = blockIdx.y * 128;
    const int colBase = blockIdx.x * 128;
    const int l  = tid & 63;
    const int wv = tid >> 6;
    const int wm = (wv >> 1) * 64;
    const int wn = (wv & 1) * 64;

    floatx4 acc[4][4] = {};

    const int r0 = tid >> 2;
    const int kj = (tid & 3) * 8;
    const unsigned short* gA0 = A + (size_t)(rowBase + r0)      * K_DIM + kj;
    const unsigned short* gA1 = A + (size_t)(rowBase + r0 + 64) * K_DIM + kj;
    const unsigned short* gB0 = B + (size_t)(colBase + r0)      * K_DIM + kj;
    const unsigned short* gB1 = B + (size_t)(colBase + r0 + 64) * K_DIM + kj;
    unsigned short* lA0 = &As[tid*8];
    unsigned short* lA1 = &As[(tid+256)*8];
    unsigned short* lB0 = &Bs[tid*8];
    unsigned short* lB1 = &Bs[(tid+256)*8];

    const int fr = l & 15;
    const int fk = (l >> 4) * 8;

    for (int kc = 0; kc < K_DIM; kc += 32){
        __syncthreads();
        GLD16(gA0 + kc, lA0);
        GLD16(gA1 + kc, lA1);
        GLD16(gB0 + kc, lB0);
        GLD16(gB1 + kc, lB1);
        __syncthreads();
        short8 af[4], bfr[4];
        #pragma unroll
        for (int i = 0; i < 4; i++)
            af[i] = *(const short8*)&As[(wm + i*16 + fr)*32 + fk];
        #pragma unroll
        for (int jj = 0; jj < 4; jj++)
            bfr[jj] = *(const short8*)&Bs[(wn + jj*16 + fr)*32 + fk];
        #pragma unroll
        for (int i = 0; i < 4; i++)
            #pragma unroll
            for (int jj = 0; jj < 4; jj++)
                acc[i][jj] = __builtin_amdgcn_mfma_f32_16x16x32_bf16(af[i], bfr[jj], acc[i][jj], 0, 0, 0);
    }

    const int ntile = blockIdx.x;
    const int l15 = l & 15;
    if (ntile < 24){
        const int gcol = colBase + wn;           // 0..3071
        const int seg  = gcol >> 10;             // 0=q, 1=k, 2=v
        const int h    = (gcol >> 6) & 15;
        if (seg < 2){
            const int segOff = (seg == 0) ? 256 : 0;
            #pragma unroll
            for (int i = 0; i < 4; i++){
                #pragma unroll
                for (int r = 0; r < 4; r++){
                    float ss = acc[i][0][r]*acc[i][0][r] + acc[i][1][r]*acc[i][1][r]
                             + acc[i][2][r]*acc[i][2][r] + acc[i][3][r]*acc[i][3][r];
                    ss = red16(ss);
                    const float rn = 1.f / fmaxf(sqrtf(ss), 1e-12f);
                    const int row = rowBase + wm + i*16 + (l >> 4)*4 + r;
                    const size_t rec = (size_t)((row & 7)*16 + h)*1024 + (row >> 3);
                    float* rp = (float*)(KQV + rec*REC + segOff);
                    #pragma unroll
                    for (int jj = 0; jj < 4; jj++)
                        rp[jj*16 + l15] = acc[i][jj][r] * rn;
                }
            }
        } else {
            #pragma unroll
            for (int i = 0; i < 4; i++){
                #pragma unroll
                for (int r = 0; r < 4; r++){
                    const int row = rowBase + wm + i*16 + (l >> 4)*4 + r;
                    const size_t rec = (size_t)((row & 7)*16 + h)*1024 + (row >> 3);
                    float* rp = (float*)(KQV + rec*REC + 512);
                    #pragma unroll
                    for (int jj = 0; jj < 4; jj++)
                        rp[jj*16 + l15] = acc[i][jj][r];
                }
            }
        }
    } else {
        const int isBeta = (ntile >= 32) ? 1 : 0;
        const float* bias = isBeta ? b_beta : b_alpha;
        const int gcol0 = colBase + wn - (isBeta ? 4096 : 3072);   // 0..960
        const int hh = gcol0 >> 6;                                  // head 0..15
        float bj[4];
        #pragma unroll
        for (int jj = 0; jj < 4; jj++) bj[jj] = bias[gcol0 + jj*16 + l15];
        #pragma unroll
        for (int i = 0; i < 4; i++){
            #pragma unroll
            for (int r = 0; r < 4; r++){
                float sum = 0.f;
                #pragma unroll
                for (int jj = 0; jj < 4; jj++) sum += sigf(acc[i][jj][r] + bj[jj]);
                sum = red16(sum);
                if (l15 == 0){
                    const int row = rowBase + wm + i*16 + (l >> 4)*4 + r;
                    const int t = row >> 3, bb = row & 7;
                    G[(((size_t)(bb*16 + hh)*1024 + t))*2 + isBeta] = sum * (1.f/64.f);
                }
            }
        }
    }
}

// ---------------- sequential scan ----------------
// 512 blocks: quarter*128+bh (same-bh quarters share an XCD since 128%8==0).
// 16 rows/block, 16 lanes x 4 state elems per row.
// Software-pipelined LDS->reg loads (1 step ahead); kq reduced in-scan.
__global__ __launch_bounds__(256) void scan_kernel(const unsigned char* __restrict__ KQV,
        const float* __restrict__ G,
        const float* __restrict__ S0, float* __restrict__ out){
    const int bh      = blockIdx.x & 127;
    const int quarter = blockIdx.x >> 7;
    const int b = bh >> 4;
    const int h = bh & 15;
    const int tid = threadIdx.x;
    const int jj  = tid & 15;              // element group within row
    const int lr  = tid >> 4;              // 0..15 row within quarter
    const int d   = quarter*16 + lr;

    __shared__ unsigned char sRec[2][CT*REC];    // 24576 B each
    __shared__ float2 sG[2][CT];

    const unsigned char* gRec = KQV + (size_t)bh * (1024*REC);
    const unsigned char* gG   = (const unsigned char*)G + (size_t)bh * (1024*8);

    // stage chunk 0
    {
        const unsigned char* src = gRec + tid*16;
        unsigned char* dst = &sRec[0][0] + tid*16;
        #pragma unroll
        for (int it = 0; it < 6; it++) GLD16(src + it*4096, dst + it*4096);
        if (tid < 16) GLD16(gG + tid*16, (unsigned char*)&sG[0][0] + tid*16);
    }

    float s[4];
    {
        const float* s0p = S0 + ((size_t)bh*64 + d)*64 + jj*4;
        float4 s4 = *(const float4*)s0p;
        s[0]=s4.x; s[1]=s4.y; s[2]=s4.z; s[3]=s4.w;
    }

    float* outP = out + (size_t)b*1024 + h*64 + d;

    for (int c = 0; c < NCHUNK; ++c){
        __syncthreads();                        // chunk c ready
        const int buf = c & 1;
        if (c + 1 < NCHUNK){                    // prefetch chunk c+1
            const unsigned char* src = gRec + (size_t)(c+1)*(CT*REC) + tid*16;
            unsigned char* dst = &sRec[buf^1][0] + tid*16;
            #pragma unroll
            for (int it = 0; it < 6; it++) GLD16(src + it*4096, dst + it*4096);
            if (tid < 16) GLD16(gG + (size_t)(c+1)*(CT*8) + tid*16,
                                (unsigned char*)&sG[buf^1][0] + tid*16);
        }

        // software pipeline: regs hold step tl; load tl+1 before computing tl
        const unsigned char* rec0 = &sRec[buf][0];
        float4 k4 = *(const float4*)(rec0 + (jj<<4));
        float4 q4 = *(const float4*)(rec0 + 256 + (jj<<4));
        float  vd = *(const float*)(rec0 + 512 + (d<<2));
        float2 g  = sG[buf][0];

        #pragma unroll
        for (int tl = 0; tl < CT; ++tl){
            const float4 kc = k4;
            const float4 qc = q4;
            const float  vc = vd;
            const float2 gc = g;
            if (tl + 1 < CT){
                const unsigned char* recn = &sRec[buf][(tl+1)*REC];
                k4 = *(const float4*)(recn + (jj<<4));
                q4 = *(const float4*)(recn + 256 + (jj<<4));
                vd = *(const float*)(recn + 512 + (d<<2));
                g  = sG[buf][tl+1];
            }

            float sk = (s[0]*kc.x + s[2]*kc.z) + (s[1]*kc.y + s[3]*kc.w);
            float sq = (s[0]*qc.x + s[2]*qc.z) + (s[1]*qc.y + s[3]*qc.w);
            float kq = (kc.x*qc.x + kc.z*qc.z) + (kc.y*qc.y + kc.w*qc.w);
            red16x3(sk, sq, kq);

            const float c1 = gc.y * (vc - gc.x * sk);
            const float o  = gc.x * sq + c1 * kq;

            s[0] = gc.x*s[0] + c1*kc.x;
            s[1] = gc.x*s[1] + c1*kc.y;
            s[2] = gc.x*s[2] + c1*kc.z;
            s[3] = gc.x*s[3] + c1*kc.w;

            if (jj == 0){
                const int t = c*CT + tl;
                outP[(size_t)t*8192] = o;
            }
        }
    }

    // S_final
    float* sf = out + (size_t)8388608 + ((size_t)bh*64 + d)*64 + jj*4;
    float4 s4; s4.x=s[0]; s4.y=s[1]; s4.z=s[2]; s4.w=s[3];
    *(float4*)sf = s4;
}

extern "C" void kernel_launch(void* const* d_in, const int* in_sizes, int n_in,
                              void* d_out, int out_size, void* d_ws, size_t ws_size,
                              hipStream_t stream){
    const float* x  = (const float*)d_in[0];
    const float* S0 = (const float*)d_in[1];
    const float* Wq = (const float*)d_in[2];
    const float* Wk = (const float*)d_in[3];
    const float* Wv = (const float*)d_in[4];
    const float* Wa = (const float*)d_in[5];
    const float* ba = (const float*)d_in[6];
    const float* Wb = (const float*)d_in[7];
    const float* bb = (const float*)d_in[8];
    float* out = (float*)d_out;

    char* ws = (char*)d_ws;
    unsigned short* Abf = (unsigned short*)ws;                    // 16,777,216 B
    unsigned short* Bbf = (unsigned short*)(ws + 16777216);       // 10,485,760 B
    unsigned char* KQV = (unsigned char*)(ws + 27262976);         // 100,663,296 B (128*1024*768)
    float* G   = (float*)(ws + 127926272);                        //  1,048,576 B -> end 128,974,848

    // conversions
    cvt_bf16<<<2048, 256, 0, stream>>>(x, Abf, (M_ROWS*K_DIM)/4);
    cvt_w<<<5120, 256, 0, stream>>>(Wq, Wk, Wv, Wa, Wb, Bbf);

    // fused projection GEMM (khat/qhat/v -> KQV; alpha/beta -> G.xy)
    dim3 gg(N_COLS/128, M_ROWS/128);   // 40 x 64
    gemm_bt<<<gg, 256, 0, stream>>>(Abf, Bbf, KQV, G, ba, bb);

    // recurrence (kq folded in)
    scan_kernel<<<512, 256, 0, stream>>>(KQV, G, S0, out);
}

// Round 6
// 429.238 us; speedup vs baseline: 1.0402x; 1.0402x over previous
//
#include <hip/hip_runtime.h>
#include <hip/hip_bf16.h>
#include <math.h>

#define T_DIM 1024
#define B_DIM 8
#define D_DIM 1024
#define H_DIM 16
#define DH 64
#define M_ROWS 8192          // T*B
#define N_COLS 5120          // 5*D
#define K_DIM 1024
#define PAD 72               // padded bf16 row length (144 B): b128-aligned, conflict-free

typedef __attribute__((ext_vector_type(8))) short short8;
typedef __attribute__((ext_vector_type(4))) float floatx4;

static __device__ __forceinline__ unsigned short f2bf(float f){
    unsigned int u = __float_as_uint(f);
    u += 0x7fff + ((u >> 16) & 1);          // RNE
    return (unsigned short)(u >> 16);
}
static __device__ __forceinline__ float sigf(float x){
    return 1.f / (1.f + __expf(-x));
}

// DPP butterfly adds on VALU pipe
#define DPPADD(x, ctrl) ((x) + __int_as_float(__builtin_amdgcn_update_dpp(0, __float_as_int(x), (ctrl), 0xF, 0xF, true)))
static __device__ __forceinline__ float red16(float x){
    x = DPPADD(x, 0xB1); x = DPPADD(x, 0x4E); x = DPPADD(x, 0x141); x = DPPADD(x, 0x140); return x;
}

// ---------------- fp32 -> bf16 conversion ----------------
__global__ void cvt_bf16(const float* __restrict__ src, unsigned short* __restrict__ dst, int n4){
    int i = blockIdx.x*blockDim.x + threadIdx.x;
    int stride = gridDim.x*blockDim.x;
    for (; i < n4; i += stride){
        float4 f = ((const float4*)src)[i];
        ushort4 o;
        o.x = f2bf(f.x); o.y = f2bf(f.y); o.z = f2bf(f.z); o.w = f2bf(f.w);
        ((ushort4*)dst)[i] = o;
    }
}

__global__ void cvt_w(const float* __restrict__ w0, const float* __restrict__ w1,
                      const float* __restrict__ w2, const float* __restrict__ w3,
                      const float* __restrict__ w4, unsigned short* __restrict__ dst){
    int i = blockIdx.x*blockDim.x + threadIdx.x;
    int seg = i >> 18;
    int off = i & 262143;
    const float* src = (seg==0)?w0:(seg==1)?w1:(seg==2)?w2:(seg==3)?w3:w4;
    float4 f = ((const float4*)src)[off];
    ushort4 o;
    o.x = f2bf(f.x); o.y = f2bf(f.y); o.z = f2bf(f.z); o.w = f2bf(f.w);
    ((ushort4*)dst)[i] = o;
}

// ---------------- NT GEMM + fused epilogue ----------------
// KQV record per (bh,t): 512 B = [khat bf16 x64 | qhat bf16 x64 | v fp32 x64]
// gates -> G[bh][t] = {alpha, beta} fp32
#define GLD16(g, l) __builtin_amdgcn_global_load_lds(                         \
    (const __attribute__((address_space(1))) void*)(g),                       \
    (__attribute__((address_space(3))) void*)(l), 16, 0, 0)

__global__ __launch_bounds__(256) void gemm_bt(const unsigned short* __restrict__ A,
                                               const unsigned short* __restrict__ B,
                                               unsigned char* __restrict__ KQV,
                                               float* __restrict__ G,
                                               const float* __restrict__ b_alpha,
                                               const float* __restrict__ b_beta){
    __shared__ unsigned short As[128*32];
    __shared__ unsigned short Bs[128*32];
    const int tid = threadIdx.x;
    const int rowBase = blockIdx.y * 128;
    const int colBase = blockIdx.x * 128;
    const int l  = tid & 63;
    const int wv = tid >> 6;
    const int wm = (wv >> 1) * 64;
    const int wn = (wv & 1) * 64;

    floatx4 acc[4][4] = {};

    const int r0 = tid >> 2;
    const int kj = (tid & 3) * 8;
    const unsigned short* gA0 = A + (size_t)(rowBase + r0)      * K_DIM + kj;
    const unsigned short* gA1 = A + (size_t)(rowBase + r0 + 64) * K_DIM + kj;
    const unsigned short* gB0 = B + (size_t)(colBase + r0)      * K_DIM + kj;
    const unsigned short* gB1 = B + (size_t)(colBase + r0 + 64) * K_DIM + kj;
    unsigned short* lA0 = &As[tid*8];
    unsigned short* lA1 = &As[(tid+256)*8];
    unsigned short* lB0 = &Bs[tid*8];
    unsigned short* lB1 = &Bs[(tid+256)*8];

    const int fr = l & 15;
    const int fk = (l >> 4) * 8;

    for (int kc = 0; kc < K_DIM; kc += 32){
        __syncthreads();
        GLD16(gA0 + kc, lA0);
        GLD16(gA1 + kc, lA1);
        GLD16(gB0 + kc, lB0);
        GLD16(gB1 + kc, lB1);
        __syncthreads();
        short8 af[4], bfr[4];
        #pragma unroll
        for (int i = 0; i < 4; i++)
            af[i] = *(const short8*)&As[(wm + i*16 + fr)*32 + fk];
        #pragma unroll
        for (int jj = 0; jj < 4; jj++)
            bfr[jj] = *(const short8*)&Bs[(wn + jj*16 + fr)*32 + fk];
        #pragma unroll
        for (int i = 0; i < 4; i++)
            #pragma unroll
            for (int jj = 0; jj < 4; jj++)
                acc[i][jj] = __builtin_amdgcn_mfma_f32_16x16x32_bf16(af[i], bfr[jj], acc[i][jj], 0, 0, 0);
    }

    const int ntile = blockIdx.x;
    const int l15 = l & 15;
    if (ntile < 24){
        const int gcol = colBase + wn;           // 0..3071
        const int seg  = gcol >> 10;             // 0=q, 1=k, 2=v
        const int h    = (gcol >> 6) & 15;
        if (seg < 2){
            const int segOff = (seg == 0) ? 128 : 0;
            #pragma unroll
            for (int i = 0; i < 4; i++){
                #pragma unroll
                for (int r = 0; r < 4; r++){
                    float ss = acc[i][0][r]*acc[i][0][r] + acc[i][1][r]*acc[i][1][r]
                             + acc[i][2][r]*acc[i][2][r] + acc[i][3][r]*acc[i][3][r];
                    ss = red16(ss);
                    const float rn = 1.f / fmaxf(sqrtf(ss), 1e-12f);
                    const int row = rowBase + wm + i*16 + (l >> 4)*4 + r;
                    const size_t rec = (size_t)((row & 7)*16 + h)*1024 + (row >> 3);
                    unsigned short* rp = (unsigned short*)(KQV + rec*512 + segOff);
                    #pragma unroll
                    for (int jj = 0; jj < 4; jj++)
                        rp[jj*16 + l15] = f2bf(acc[i][jj][r] * rn);
                }
            }
        } else {
            #pragma unroll
            for (int i = 0; i < 4; i++){
                #pragma unroll
                for (int r = 0; r < 4; r++){
                    const int row = rowBase + wm + i*16 + (l >> 4)*4 + r;
                    const size_t rec = (size_t)((row & 7)*16 + h)*1024 + (row >> 3);
                    float* vp = (float*)(KQV + rec*512 + 256);
                    #pragma unroll
                    for (int jj = 0; jj < 4; jj++)
                        vp[jj*16 + l15] = acc[i][jj][r];
                }
            }
        }
    } else {
        const int isBeta = (ntile >= 32) ? 1 : 0;
        const float* bias = isBeta ? b_beta : b_alpha;
        const int gcol0 = colBase + wn - (isBeta ? 4096 : 3072);
        const int hh = gcol0 >> 6;
        float bj[4];
        #pragma unroll
        for (int jj = 0; jj < 4; jj++) bj[jj] = bias[gcol0 + jj*16 + l15];
        #pragma unroll
        for (int i = 0; i < 4; i++){
            #pragma unroll
            for (int r = 0; r < 4; r++){
                float sum = 0.f;
                #pragma unroll
                for (int jj = 0; jj < 4; jj++) sum += sigf(acc[i][jj][r] + bj[jj]);
                sum = red16(sum);
                if (l15 == 0){
                    const int row = rowBase + wm + i*16 + (l >> 4)*4 + r;
                    const int t = row >> 3, bb = row & 7;
                    G[(((size_t)(bb*16 + hh)*1024 + t))*2 + isBeta] = sum * (1.f/64.f);
                }
            }
        }
    }
}

// ---------------- Phase A: per-(bh,chunk) coefficients ----------------
// outputs: Wtg = (I+C)^-1 diag(be)  (bf16 64x64), Ng[t,s] = (r_t/r_s)(q_t.k_s) s<=t (bf16),
//          rg = cumulative decay r_t (fp32)
__global__ __launch_bounds__(256) void phasea(const unsigned char* __restrict__ KQV,
                                              const float* __restrict__ G,
                                              unsigned short* __restrict__ Wtg,
                                              unsigned short* __restrict__ Ng,
                                              float* __restrict__ rg){
    __shared__ unsigned short sKa[64*PAD], sQa[64*PAD];
    __shared__ float sAB[128];
    __shared__ float sKK[4096];
    __shared__ float sX[4096];
    __shared__ float sR[64], sRi[64];

    const int unitIdx = blockIdx.x;
    const int bh = unitIdx >> 4, c = unitIdx & 15;
    const int tid = threadIdx.x;
    const int w = tid>>6, l = tid&63, l15 = l&15, quad = l>>4;
    const unsigned char* gRec = KQV + ((size_t)bh*1024 + c*64)*512;

    #pragma unroll
    for (int it=0; it<2; ++it){
        int flat = it*256 + tid, t = flat>>3, i8 = flat&7;
        float4 kv = *(const float4*)(gRec + t*512 + i8*16);
        float4 qv = *(const float4*)(gRec + t*512 + 128 + i8*16);
        *(float4*)&sKa[t*PAD + i8*8] = kv;
        *(float4*)&sQa[t*PAD + i8*8] = qv;
    }
    if (tid < 64){
        float2 ab = *(const float2*)(G + ((size_t)bh*1024 + c*64 + tid)*2);
        sAB[tid*2] = ab.x; sAB[tid*2+1] = ab.y;
    }
    __syncthreads();
    if (tid < 64){
        float p = sAB[tid*2];
        #pragma unroll
        for (int off=1; off<64; off<<=1){
            float y = __shfl_up(p, off);
            if (tid >= off) p *= y;
        }
        sR[tid] = p; sRi[tid] = 1.f/p;
    }
    __syncthreads();

    // KK (waves 0,1) / QK->N (waves 2,3)
    {
        const int isQK = w >> 1;
        const int tmb = (w & 1)*2;
        floatx4 acc[2][4] = {};
        #pragma unroll
        for (int ks=0; ks<2; ++ks){
            short8 aA[2]; short8 bB[4];
            #pragma unroll
            for (int i=0;i<2;++i)
                aA[i] = *(const short8*)&((isQK? sQa : sKa)[((tmb+i)*16 + l15)*PAD + ks*32 + quad*8]);
            #pragma unroll
            for (int j2=0;j2<4;++j2)
                bB[j2] = *(const short8*)&sKa[(j2*16 + l15)*PAD + ks*32 + quad*8];
            #pragma unroll
            for (int i=0;i<2;++i)
                #pragma unroll
                for (int j2=0;j2<4;++j2)
                    acc[i][j2] = __builtin_amdgcn_mfma_f32_16x16x32_bf16(aA[i], bB[j2], acc[i][j2], 0,0,0);
        }
        #pragma unroll
        for (int i=0;i<2;++i){
            #pragma unroll
            for (int j2=0;j2<4;++j2){
                #pragma unroll
                for (int r=0;r<4;++r){
                    int t = (tmb+i)*16 + quad*4 + r;
                    int s = j2*16 + l15;
                    float ratio = sR[t]*sRi[s];
                    if (!isQK){
                        sKK[t*64+s] = (s < t) ? sAB[t*2+1]*ratio*acc[i][j2][r] : 0.f;
                    } else {
                        float nv = (s <= t) ? ratio*acc[i][j2][r] : 0.f;
                        Ng[(size_t)unitIdx*4096 + t*64 + s] = f2bf(nv);
                    }
                }
            }
        }
    }
    #pragma unroll
    for (int e=0; e<16; ++e) sX[tid + e*256] = 0.f;
    __syncthreads();

    // X = (I+C)^-1, column-parallel forward substitution on wave 0
    if (tid < 64){
        const int s = tid;
        if (s == 0) sX[0] = 1.f;
        for (int t=1; t<64; ++t){
            float a0=0.f, a1=0.f;
            int r = 0;
            for (; r+1 < t; r += 2){
                a0 += sKK[t*64+r]   * sX[r*64+s];
                a1 += sKK[t*64+r+1] * sX[(r+1)*64+s];
            }
            if (r < t) a0 += sKK[t*64+r]*sX[r*64+s];
            sX[t*64+s] = (s==t) ? 1.f : -(a0+a1);
        }
    }
    __syncthreads();

    #pragma unroll
    for (int e=0; e<16; ++e){
        int flat = tid + e*256;
        int s = flat&63;
        Wtg[(size_t)unitIdx*4096 + flat] = f2bf(sX[flat]*sAB[s*2+1]);
    }
    if (tid < 64) rg[(size_t)unitIdx*64 + tid] = sR[tid];
}

// ---------------- Phase B: sequential chunk scan via MFMA ----------------
// 256 blocks = (half*128 + bh); block owns 32 d-rows of S (in registers).
__global__ __launch_bounds__(256) void chunk_scan(const unsigned char* __restrict__ KQV,
                                                  const unsigned short* __restrict__ Wtg,
                                                  const unsigned short* __restrict__ Ng,
                                                  const float* __restrict__ rg,
                                                  const float* __restrict__ S0g,
                                                  float* __restrict__ out){
    __shared__ unsigned short sK[64*PAD], sQ[64*PAD], sWt[64*PAD];
    __shared__ unsigned short sN[2][64*PAD];
    __shared__ unsigned short sUt[32*PAD];
    __shared__ unsigned short sKtU[64*PAD];   // rows 0..31 double as RHS^T early in chunk
    __shared__ unsigned short sS0b[32*PAD];
    __shared__ float sr[2][64];

    const int bh = blockIdx.x & 127;
    const int half = blockIdx.x >> 7;
    const int b = bh >> 4, h = bh & 15;
    const int tid = threadIdx.x;
    const int w = tid >> 6, l = tid & 63, l15 = l & 15, quad = l >> 4;
    const int t0 = w*16 + quad*4;
    const int tmS = w & 1, tnS0 = (w>>1)*2;
    const int d2base = tmS*16 + quad*4;
    const unsigned char* gRec = KQV + (size_t)bh * (1024*512);
    const size_t outBase = (size_t)b*1024 + h*64 + half*32;

    float4 kst[2], qst[2], wst[2], nst[2];
    float rst = 0.f;
    float vCur[8], vNext[8];
    floatx4 Sreg[2];

    // prologue: chunk 0
    {
        const int unit = bh*16;
        #pragma unroll
        for (int it=0; it<2; ++it){
            int flat = it*256 + tid, t = flat>>3, i8 = flat&7;
            kst[it] = *(const float4*)(gRec + t*512 +       i8*16);
            qst[it] = *(const float4*)(gRec + t*512 + 128 + i8*16);
            wst[it] = *(const float4*)((const unsigned char*)Wtg + (size_t)unit*8192 + (size_t)flat*16);
            nst[it] = *(const float4*)((const unsigned char*)Ng  + (size_t)unit*8192 + (size_t)flat*16);
        }
        if (tid < 64) rst = rg[(size_t)unit*64 + tid];
        #pragma unroll
        for (int tn=0; tn<2; ++tn)
            #pragma unroll
            for (int r=0; r<4; ++r)
                vCur[tn*4+r] = *(const float*)(gRec + (t0+r)*512 + 256 + (half*32 + tn*16 + l15)*4);
        #pragma unroll
        for (int j=0;j<2;++j)
            #pragma unroll
            for (int r=0;r<4;++r)
                Sreg[j][r] = S0g[(size_t)bh*4096 + (half*32 + d2base + r)*64 + (tnS0+j)*16 + l15];
        #pragma unroll
        for (int it=0; it<2; ++it){
            int flat = it*256 + tid, t = flat>>3, i8 = flat&7;
            *(float4*)&sK[t*PAD + i8*8]    = kst[it];
            *(float4*)&sQ[t*PAD + i8*8]    = qst[it];
            *(float4*)&sWt[t*PAD + i8*8]   = wst[it];
            *(float4*)&sN[0][t*PAD + i8*8] = nst[it];
        }
        if (tid < 64) sr[0][tid] = rst;
        #pragma unroll
        for (int j=0;j<2;++j)
            #pragma unroll
            for (int r=0;r<4;++r)
                sS0b[(d2base+r)*PAD + (tnS0+j)*16 + l15] = f2bf(Sreg[j][r]);
    }
    __syncthreads();

    for (int c=0; c<16; ++c){
        const int buf = c & 1;
        if (c < 15){
            const int unit = bh*16 + c + 1;
            const unsigned char* gRecN = gRec + (size_t)(c+1)*64*512;
            #pragma unroll
            for (int it=0; it<2; ++it){
                int flat = it*256 + tid, t = flat>>3, i8 = flat&7;
                kst[it] = *(const float4*)(gRecN + t*512 +       i8*16);
                qst[it] = *(const float4*)(gRecN + t*512 + 128 + i8*16);
                wst[it] = *(const float4*)((const unsigned char*)Wtg + (size_t)unit*8192 + (size_t)flat*16);
                nst[it] = *(const float4*)((const unsigned char*)Ng  + (size_t)unit*8192 + (size_t)flat*16);
            }
            if (tid < 64) rst = rg[(size_t)unit*64 + tid];
            #pragma unroll
            for (int tn=0; tn<2; ++tn)
                #pragma unroll
                for (int r=0;r<4;++r)
                    vNext[tn*4+r] = *(const float*)(gRecN + (t0+r)*512 + 256 + (half*32 + tn*16 + l15)*4);
        }

        // stage 1: PT = K*S0^T, OB = Q*S0^T  (C-frag: row=t, col=d)
        floatx4 accPT[2] = {}; floatx4 accOB[2] = {};
        #pragma unroll
        for (int ks=0; ks<2; ++ks){
            short8 aK = *(const short8*)&sK[(w*16 + l15)*PAD + ks*32 + quad*8];
            short8 aQ = *(const short8*)&sQ[(w*16 + l15)*PAD + ks*32 + quad*8];
            #pragma unroll
            for (int tn=0; tn<2; ++tn){
                short8 bS = *(const short8*)&sS0b[(tn*16 + l15)*PAD + ks*32 + quad*8];
                accPT[tn] = __builtin_amdgcn_mfma_f32_16x16x32_bf16(aK, bS, accPT[tn], 0,0,0);
                accOB[tn] = __builtin_amdgcn_mfma_f32_16x16x32_bf16(aQ, bS, accOB[tn], 0,0,0);
            }
        }
        float r4[4];
        #pragma unroll
        for (int r=0;r<4;++r) r4[r] = sr[buf][t0+r];
        #pragma unroll
        for (int tn=0; tn<2; ++tn){
            float x0 = vCur[tn*4+0] - r4[0]*accPT[tn][0];
            float x1 = vCur[tn*4+1] - r4[1]*accPT[tn][1];
            float x2 = vCur[tn*4+2] - r4[2]*accPT[tn][2];
            float x3 = vCur[tn*4+3] - r4[3]*accPT[tn][3];
            uint2 uu;
            uu.x = (unsigned)f2bf(x0) | ((unsigned)f2bf(x1)<<16);
            uu.y = (unsigned)f2bf(x2) | ((unsigned)f2bf(x3)<<16);
            *(uint2*)&sKtU[(tn*16 + l15)*PAD + t0] = uu;     // RHS^T[d][t]
        }
        __syncthreads();   // A

        // stage 2: U = Wt * RHS^T
        floatx4 accU[2] = {};
        #pragma unroll
        for (int ks=0; ks<2; ++ks){
            short8 aW = *(const short8*)&sWt[(w*16 + l15)*PAD + ks*32 + quad*8];
            #pragma unroll
            for (int tn=0; tn<2; ++tn){
                short8 bR = *(const short8*)&sKtU[(tn*16 + l15)*PAD + ks*32 + quad*8];
                accU[tn] = __builtin_amdgcn_mfma_f32_16x16x32_bf16(aW, bR, accU[tn], 0,0,0);
            }
        }
        __syncthreads();   // B'

        // stage-2 epilogue: write U^T; build scaled K^T (overwrites RHS region)
        #pragma unroll
        for (int tn=0; tn<2; ++tn){
            uint2 uu;
            uu.x = (unsigned)f2bf(accU[tn][0]) | ((unsigned)f2bf(accU[tn][1])<<16);
            uu.y = (unsigned)f2bf(accU[tn][2]) | ((unsigned)f2bf(accU[tn][3])<<16);
            *(uint2*)&sUt[(tn*16 + l15)*PAD + t0] = uu;
        }
        {
            const float rl = sr[buf][63];
            const int e = tid >> 2, sb = (tid & 3)*16;
            #pragma unroll
            for (int j2=0; j2<16; ++j2){
                int s = sb + j2;
                float kv = __uint_as_float((unsigned)sK[s*PAD + e] << 16);
                sKtU[e*PAD + s] = f2bf(kv * (rl / sr[buf][s]));
            }
        }
        __syncthreads();   // B

        // stage 3: O = diag(r)*OB + N*U^T ;  S = rl*S0 + U^T * Ktilde^T
        floatx4 accO[2];
        #pragma unroll
        for (int tn=0;tn<2;++tn)
            #pragma unroll
            for (int r=0;r<4;++r) accO[tn][r] = r4[r]*accOB[tn][r];
        #pragma unroll
        for (int ks=0; ks<2; ++ks){
            short8 aN = *(const short8*)&sN[buf][(w*16 + l15)*PAD + ks*32 + quad*8];
            #pragma unroll
            for (int tn=0; tn<2; ++tn){
                short8 bU = *(const short8*)&sUt[(tn*16 + l15)*PAD + ks*32 + quad*8];
                accO[tn] = __builtin_amdgcn_mfma_f32_16x16x32_bf16(aN, bU, accO[tn], 0,0,0);
            }
        }
        const float rl = sr[buf][63];
        floatx4 accS[2];
        #pragma unroll
        for (int j=0;j<2;++j)
            #pragma unroll
            for (int r=0;r<4;++r) accS[j][r] = rl*Sreg[j][r];
        #pragma unroll
        for (int ks=0; ks<2; ++ks){
            short8 aU = *(const short8*)&sUt[(tmS*16 + l15)*PAD + ks*32 + quad*8];
            #pragma unroll
            for (int j=0;j<2;++j){
                short8 bK = *(const short8*)&sKtU[((tnS0+j)*16 + l15)*PAD + ks*32 + quad*8];
                accS[j] = __builtin_amdgcn_mfma_f32_16x16x32_bf16(aU, bK, accS[j], 0,0,0);
            }
        }
        #pragma unroll
        for (int j=0;j<2;++j) Sreg[j] = accS[j];

        #pragma unroll
        for (int tn=0;tn<2;++tn)
            #pragma unroll
            for (int r=0;r<4;++r)
                out[(size_t)(c*64 + t0 + r)*8192 + outBase + tn*16 + l15] = accO[tn][r];
        #pragma unroll
        for (int j=0;j<2;++j)
            #pragma unroll
            for (int r=0;r<4;++r)
                sS0b[(d2base + r)*PAD + (tnS0+j)*16 + l15] = f2bf(Sreg[j][r]);

        if (c < 15){
            #pragma unroll
            for (int it=0; it<2; ++it){
                int flat = it*256 + tid, t = flat>>3, i8 = flat&7;
                *(float4*)&sK[t*PAD + i8*8]         = kst[it];
                *(float4*)&sQ[t*PAD + i8*8]         = qst[it];
                *(float4*)&sWt[t*PAD + i8*8]        = wst[it];
                *(float4*)&sN[buf^1][t*PAD + i8*8]  = nst[it];
            }
            if (tid < 64) sr[buf^1][tid] = rst;
            #pragma unroll
            for (int q2=0;q2<8;++q2) vCur[q2] = vNext[q2];
        }
        __syncthreads();   // end of chunk
    }

    // final state
    #pragma unroll
    for (int j=0;j<2;++j)
        #pragma unroll
        for (int r=0;r<4;++r)
            out[(size_t)8388608 + (size_t)bh*4096 + (half*32 + d2base + r)*64 + (tnS0+j)*16 + l15] = Sreg[j][r];
}

extern "C" void kernel_launch(void* const* d_in, const int* in_sizes, int n_in,
                              void* d_out, int out_size, void* d_ws, size_t ws_size,
                              hipStream_t stream){
    const float* x  = (const float*)d_in[0];
    const float* S0 = (const float*)d_in[1];
    const float* Wq = (const float*)d_in[2];
    const float* Wk = (const float*)d_in[3];
    const float* Wv = (const float*)d_in[4];
    const float* Wa = (const float*)d_in[5];
    const float* ba = (const float*)d_in[6];
    const float* Wb = (const float*)d_in[7];
    const float* bb = (const float*)d_in[8];
    float* out = (float*)d_out;

    char* ws = (char*)d_ws;
    unsigned short* Abf = (unsigned short*)ws;                    // 16,777,216
    unsigned short* Bbf = (unsigned short*)(ws + 16777216);       // 10,485,760
    unsigned char*  KQV = (unsigned char*) (ws + 27262976);       // 67,108,864 (128*1024*512)
    float*          G   = (float*)         (ws + 94371840);       //  1,048,576
    unsigned short* Wtg = (unsigned short*)(ws + 95420416);       // 16,777,216 (2048*4096 bf16)
    unsigned short* Ng  = (unsigned short*)(ws + 112197632);      // 16,777,216
    float*          rg  = (float*)         (ws + 128974848);      //    524,288  -> end 129,499,136

    cvt_bf16<<<2048, 256, 0, stream>>>(x, Abf, (M_ROWS*K_DIM)/4);
    cvt_w<<<5120, 256, 0, stream>>>(Wq, Wk, Wv, Wa, Wb, Bbf);

    dim3 gg(N_COLS/128, M_ROWS/128);   // 40 x 64
    gemm_bt<<<gg, 256, 0, stream>>>(Abf, Bbf, KQV, G, ba, bb);

    phasea<<<2048, 256, 0, stream>>>(KQV, G, Wtg, Ng, rg);

    chunk_scan<<<256, 256, 0, stream>>>(KQV, Wtg, Ng, rg, S0, out);
}